// Round 1
// baseline (552.396 us; speedup 1.0000x reference)
//
#include <hip/hip_runtime.h>
#include <stdint.h>

typedef __attribute__((ext_vector_type(8))) short short8;
typedef __attribute__((ext_vector_type(4))) float f32x4;
typedef __attribute__((ext_vector_type(4))) unsigned short ushort4v;
typedef __attribute__((ext_vector_type(4))) float float4v;
typedef __attribute__((ext_vector_type(4))) int int4v;

#define GLL16(gp, lp)                                                        \
  __builtin_amdgcn_global_load_lds(                                          \
      (const __attribute__((address_space(1))) void*)(gp),                   \
      (__attribute__((address_space(3))) void*)(lp), 16, 0, 0)

__device__ __forceinline__ unsigned short f2bf(float f) {
  union { float f; unsigned u; } v; v.f = f;
  unsigned r = v.u + 0x7FFFu + ((v.u >> 16) & 1u);
  return (unsigned short)(r >> 16);
}
__device__ __forceinline__ float bf2f(unsigned short h) {
  union { unsigned u; float f; } v; v.u = ((unsigned)h) << 16;
  return v.f;
}

// ---------------- cast fp32 -> bf16, concat weights & biases ----------------
__global__ __launch_bounds__(256) void cast_kernel(
    const float* __restrict__ x, const float* __restrict__ Wq,
    const float* __restrict__ Wk, const float* __restrict__ Wv,
    const float* __restrict__ Wo, const float* __restrict__ bq,
    const float* __restrict__ bk, const float* __restrict__ bv,
    unsigned short* __restrict__ xb, unsigned short* __restrict__ wqkv,
    unsigned short* __restrict__ wob, float* __restrict__ biasq) {
  const int X4 = 2097152, W4 = 1048576;            // float4 counts
  const int total = X4 + 4 * W4 + 1536;
  for (int i = blockIdx.x * 256 + threadIdx.x; i < total; i += gridDim.x * 256) {
    if (i < X4 + 4 * W4) {
      const float* src; unsigned short* dst;
      if (i < X4) { src = x + (size_t)i * 4; dst = xb + (size_t)i * 4; }
      else {
        int j = i - X4;
        if (j < 3 * W4) {
          const float* w = (j < W4) ? Wq : (j < 2 * W4 ? Wk : Wv);
          int j0 = (j < W4) ? j : (j < 2 * W4 ? j - W4 : j - 2 * W4);
          src = w + (size_t)j0 * 4; dst = wqkv + (size_t)j * 4;
        } else {
          int j0 = j - 3 * W4; src = Wo + (size_t)j0 * 4; dst = wob + (size_t)j0 * 4;
        }
      }
      float4v v = *(const float4v*)src;
      ushort4v o; o.x = f2bf(v.x); o.y = f2bf(v.y); o.z = f2bf(v.z); o.w = f2bf(v.w);
      *(ushort4v*)dst = o;
    } else {
      int j = i - (X4 + 4 * W4);                   // 0..1535 -> 6144 floats
      const float* src = (j < 512) ? bq + j * 4
                        : (j < 1024 ? bk + (j - 512) * 4 : bv + (j - 1024) * 4);
      *(float4v*)(biasq + j * 4) = *(const float4v*)src;
    }
  }
}

// ---------------- per-64x64-tile mask summary (1 = all nonzero) ----------------
__global__ __launch_bounds__(256) void maskflag_kernel(const int* __restrict__ mask,
                                                       int* __restrict__ flags) {
  const int bid = blockIdx.x;                      // b*1024 + qt*32 + kt
  const int b = bid >> 10, rem = bid & 1023, qt = rem >> 5, kt = rem & 31;
  const int t = threadIdx.x;
  const int* mb = mask + (size_t)b * 4194304;
  int ok = 1;
#pragma unroll
  for (int j = 0; j < 4; ++j) {
    int flat = t * 16 + j * 4;
    int r = flat >> 6, c = flat & 63;
    int4v v = *(const int4v*)(mb + (size_t)(qt * 64 + r) * 2048 + kt * 64 + c);
    ok &= (v.x != 0) & (v.y != 0) & (v.z != 0) & (v.w != 0);
  }
  int all = __syncthreads_and(ok);
  if (t == 0) flags[bid] = all;
}

// ---------------- m97-style bf16 GEMM: C[m,n] = A[m,:] . B[n,:] + bias[n] ----------------
template <bool OUT_BF16>
__global__ __launch_bounds__(256) void gemm_bt(
    const unsigned short* __restrict__ A, const unsigned short* __restrict__ B,
    void* __restrict__ C, const float* __restrict__ bias, int N, int K) {
  __shared__ unsigned short As[128 * 64];
  __shared__ unsigned short Bs[128 * 64];
  const int tid = threadIdx.x, lane = tid & 63;
  const int wid = __builtin_amdgcn_readfirstlane(tid >> 6);
  const int wr = wid >> 1, wc = wid & 1;
  const int bm = blockIdx.y, bn = blockIdx.x;
  const int g = lane >> 4, q15 = lane & 15;
  f32x4 acc[4][4];
#pragma unroll
  for (int i = 0; i < 4; ++i)
#pragma unroll
    for (int j = 0; j < 4; ++j) acc[i][j] = f32x4{0.f, 0.f, 0.f, 0.f};
  const size_t ldab = (size_t)K * 2;               // row stride bytes
  const int nkt = K >> 6;
  for (int kt = 0; kt < nkt; ++kt) {
#pragma unroll
    for (int i = 0; i < 4; ++i) {
      int c = i * 4 + wid;
      int o = c * 1024 + lane * 16;
      int row = o >> 7, colb = o & 127;            // 128B rows (64 bf16)
      GLL16((const char*)A + (size_t)(bm * 128 + row) * ldab + kt * 128 + colb,
            (char*)As + c * 1024);
      GLL16((const char*)B + (size_t)(bn * 128 + row) * ldab + kt * 128 + colb,
            (char*)Bs + c * 1024);
    }
    __syncthreads();
#pragma unroll
    for (int kk = 0; kk < 2; ++kk) {
      short8 af[4], bfv[4];
#pragma unroll
      for (int mf = 0; mf < 4; ++mf)
        af[mf] = *(const short8*)((const char*)As +
                 (wr * 64 + mf * 16 + q15) * 128 + kk * 64 + g * 16);
#pragma unroll
      for (int nf = 0; nf < 4; ++nf)
        bfv[nf] = *(const short8*)((const char*)Bs +
                  (wc * 64 + nf * 16 + q15) * 128 + kk * 64 + g * 16);
#pragma unroll
      for (int mf = 0; mf < 4; ++mf)
#pragma unroll
        for (int nf = 0; nf < 4; ++nf)
          acc[mf][nf] = __builtin_amdgcn_mfma_f32_16x16x32_bf16(
              af[mf], bfv[nf], acc[mf][nf], 0, 0, 0);
    }
    __syncthreads();
  }
#pragma unroll
  for (int nf = 0; nf < 4; ++nf) {
    int col = bn * 128 + wc * 64 + nf * 16 + q15;
    float bv = bias[col];
#pragma unroll
    for (int mf = 0; mf < 4; ++mf) {
#pragma unroll
      for (int r = 0; r < 4; ++r) {
        int row = bm * 128 + wr * 64 + mf * 16 + g * 4 + r;
        float v = acc[mf][nf][r] + bv;
        if (OUT_BF16)
          ((unsigned short*)C)[(size_t)row * N + col] = f2bf(v);
        else
          ((float*)C)[(size_t)row * N + col] = v;
      }
    }
  }
}

// ---------------- L2-norm q,k in place; V -> V^T[b,h,128,S] ----------------
__global__ __launch_bounds__(256) void norm_vt_kernel(
    unsigned short* __restrict__ QKV, unsigned short* __restrict__ VT,
    const float* __restrict__ scale_p) {
  __shared__ unsigned short vt[128 * 72];          // 72 pad: 144B rows, 16B aligned
  const int bid = blockIdx.x;                      // b*512 + h*32 + st
  const int b = bid >> 9, h = (bid >> 5) & 15, st = bid & 31;
  const int t = threadIdx.x;
  const int r = t >> 2, qd = t & 3;                // 64 rows x 4 quarters of 32
  const float scale = scale_p[0];
  unsigned short* rowp = QKV + (size_t)(b * 2048 + st * 64 + r) * 6144;
#pragma unroll
  for (int part = 0; part < 2; ++part) {           // 0=q (scaled), 1=k
    unsigned short* p = rowp + part * 2048 + h * 128 + qd * 32;
    short8 v[4];
    float ss = 0.f;
#pragma unroll
    for (int j = 0; j < 4; ++j) {
      v[j] = *(const short8*)(p + j * 8);
#pragma unroll
      for (int e = 0; e < 8; ++e) {
        float f = bf2f((unsigned short)v[j][e]);
        ss += f * f;
      }
    }
    ss += __shfl_xor(ss, 1, 64);
    ss += __shfl_xor(ss, 2, 64);
    float inv = 1.0f / fmaxf(sqrtf(ss), 1e-12f);
    if (part == 0) inv *= scale;
#pragma unroll
    for (int j = 0; j < 4; ++j) {
      short8 w;
#pragma unroll
      for (int e = 0; e < 8; ++e)
        w[e] = (short)f2bf(bf2f((unsigned short)v[j][e]) * inv);
      *(short8*)(p + j * 8) = w;
    }
  }
  {                                                // V tile transpose via LDS
    const unsigned short* p = rowp + 4096 + h * 128 + qd * 32;
#pragma unroll
    for (int j = 0; j < 4; ++j) {
      short8 v = *(const short8*)(p + j * 8);
#pragma unroll
      for (int e = 0; e < 8; ++e) {
        int d = qd * 32 + j * 8 + e;
        vt[d * 72 + r] = (unsigned short)v[e];
      }
    }
  }
  __syncthreads();
  {
    const int d = t >> 1, half = t & 1;
    unsigned short* dst = VT + ((size_t)(b * 16 + h) * 128 + d) * 2048 + st * 64 + half * 32;
#pragma unroll
    for (int j = 0; j < 4; ++j)
      *(short8*)(dst + j * 8) = *(const short8*)(&vt[d * 72 + half * 32 + j * 8]);
  }
}

// ---------------- flash attention: per (b,h,64 q-rows) block ----------------
__global__ __launch_bounds__(256) void flash_kernel(
    const unsigned short* __restrict__ QKV, const unsigned short* __restrict__ VT,
    const int* __restrict__ flags, const int* __restrict__ mask,
    unsigned short* __restrict__ ctx) {
  __shared__ unsigned short Ks[64 * 128];          // [key][d] swizzled, 256B rows
  __shared__ unsigned short Vs[128 * 64];          // [d][key] swizzled, 128B rows
  __shared__ unsigned short Ps[4 * 16 * 64];       // per-wave P [q][key], 128B rows
  const int tid = threadIdx.x, lane = tid & 63;
  const int wid = __builtin_amdgcn_readfirstlane(tid >> 6);
  const int g = lane >> 4, q15 = lane & 15;
  const int bid = blockIdx.x;                      // b*512 + h*32 + qt
  const int b = bid >> 9, h = (bid >> 5) & 15, qt = bid & 31;

  // Q fragments (A operand): row = q15, k = g*8+e per kk
  short8 qf[4];
  {
    const char* qbase = (const char*)QKV +
        (size_t)(b * 2048 + qt * 64 + wid * 16 + q15) * 12288 + h * 256;
#pragma unroll
    for (int kk = 0; kk < 4; ++kk)
      qf[kk] = *(const short8*)(qbase + kk * 64 + g * 16);
  }
  f32x4 o[8];
#pragma unroll
  for (int i = 0; i < 8; ++i) o[i] = f32x4{0.f, 0.f, 0.f, 0.f};
  float mrun[4] = {-__builtin_inff(), -__builtin_inff(), -__builtin_inff(), -__builtin_inff()};
  float lrun[4] = {0.f, 0.f, 0.f, 0.f};
  char* PsW = (char*)Ps + wid * 2048;

  for (int kt = 0; kt < 32; ++kt) {
    // ---- stage K tile [64][128] and V^T tile [128][64], XOR-swizzled source ----
#pragma unroll
    for (int i = 0; i < 8; ++i) {
      int c = i * 4 + wid;
      if (c < 16) {                                // K chunk: 256B rows
        int off = c * 1024 + lane * 16;
        int row = off >> 8, colb = off & 255;
        int scol = colb ^ ((row & 7) << 4);
        GLL16((const char*)QKV + (size_t)(b * 2048 + kt * 64 + row) * 12288 +
                  4096 + h * 256 + scol,
              (char*)Ks + c * 1024);
      } else {                                     // V^T chunk: 128B rows
        int c2 = c - 16;
        int off = c2 * 1024 + lane * 16;
        int d = off >> 7, colb = off & 127;
        int scol = colb ^ ((d & 7) << 4);
        GLL16((const char*)VT + ((size_t)(b * 16 + h) * 128 + d) * 4096 +
                  kt * 128 + scol,
              (char*)Vs + c2 * 1024);
      }
    }
    __syncthreads();

    // ---- S = Q . K^T  (C: row=q=4g+reg, col=key=q15+16nf) ----
    f32x4 s[4];
#pragma unroll
    for (int nf = 0; nf < 4; ++nf) s[nf] = f32x4{0.f, 0.f, 0.f, 0.f};
#pragma unroll
    for (int nf = 0; nf < 4; ++nf) {
      int key = nf * 16 + q15;
      const char* kb = (const char*)Ks + key * 256;
      int sw = (key & 7) << 4;
#pragma unroll
      for (int kk = 0; kk < 4; ++kk) {
        short8 kf = *(const short8*)(kb + ((kk * 64 + g * 16) ^ sw));
        s[nf] = __builtin_amdgcn_mfma_f32_16x16x32_bf16(qf[kk], kf, s[nf], 0, 0, 0);
      }
    }

    // ---- mask (fast path: tile flag says all nonzero) ----
    if (flags[b * 1024 + qt * 32 + kt] == 0) {
#pragma unroll
      for (int nf = 0; nf < 4; ++nf)
#pragma unroll
        for (int r = 0; r < 4; ++r) {
          int q = qt * 64 + wid * 16 + g * 4 + r;
          int k = kt * 64 + nf * 16 + q15;
          if (mask[(size_t)b * 4194304 + (size_t)q * 2048 + k] == 0)
            s[nf][r] = -__builtin_inff();
        }
    }

    // ---- online softmax over this tile's 64 keys ----
    float rmax[4];
#pragma unroll
    for (int r = 0; r < 4; ++r)
      rmax[r] = fmaxf(fmaxf(s[0][r], s[1][r]), fmaxf(s[2][r], s[3][r]));
#pragma unroll
    for (int st = 1; st < 16; st <<= 1)
#pragma unroll
      for (int r = 0; r < 4; ++r)
        rmax[r] = fmaxf(rmax[r], __shfl_xor(rmax[r], st, 64));
    float sc_[4];
#pragma unroll
    for (int r = 0; r < 4; ++r) {
      float mn = fmaxf(mrun[r], rmax[r]);
      sc_[r] = __expf(mrun[r] - mn);
      mrun[r] = mn;
      lrun[r] *= sc_[r];
    }
#pragma unroll
    for (int d0 = 0; d0 < 8; ++d0)
#pragma unroll
      for (int r = 0; r < 4; ++r) o[d0][r] *= sc_[r];
    float rs[4] = {0.f, 0.f, 0.f, 0.f};
#pragma unroll
    for (int nf = 0; nf < 4; ++nf)
#pragma unroll
      for (int r = 0; r < 4; ++r) {
        float p = __expf(s[nf][r] - mrun[r]);
        s[nf][r] = p;
        rs[r] += p;
      }
#pragma unroll
    for (int st = 1; st < 16; st <<= 1)
#pragma unroll
      for (int r = 0; r < 4; ++r) rs[r] += __shfl_xor(rs[r], st, 64);
#pragma unroll
    for (int r = 0; r < 4; ++r) lrun[r] += rs[r];

    // ---- P -> LDS (wave-private, swizzled by (row>>2)&3) ----
#pragma unroll
    for (int nf = 0; nf < 4; ++nf)
#pragma unroll
      for (int r = 0; r < 4; ++r) {
        int qq = g * 4 + r;
        int kcol = nf * 16 + q15;
        int addr = qq * 128 + ((2 * kcol) ^ ((g & 3) << 4));
        *(unsigned short*)(PsW + addr) = f2bf(s[nf][r]);
      }

    // ---- O += P . V ----
#pragma unroll
    for (int kk2 = 0; kk2 < 2; ++kk2) {
      short8 pf = *(const short8*)(PsW + q15 * 128 +
                   ((kk2 * 64 + g * 16) ^ (((q15 >> 2) & 3) << 4)));
#pragma unroll
      for (int d0 = 0; d0 < 8; ++d0) {
        int d = d0 * 16 + q15;
        short8 vf = *(const short8*)((const char*)Vs + d * 128 +
                     ((kk2 * 64 + g * 16) ^ ((d & 7) << 4)));
        o[d0] = __builtin_amdgcn_mfma_f32_16x16x32_bf16(pf, vf, o[d0], 0, 0, 0);
      }
    }
    __syncthreads();
  }

  // ---- normalize and write ctx [4096][2048] bf16 ----
  float inv[4];
#pragma unroll
  for (int r = 0; r < 4; ++r) inv[r] = 1.0f / lrun[r];
#pragma unroll
  for (int d0 = 0; d0 < 8; ++d0)
#pragma unroll
    for (int r = 0; r < 4; ++r) {
      int row = b * 2048 + qt * 64 + wid * 16 + g * 4 + r;
      int col = h * 128 + d0 * 16 + q15;
      ctx[(size_t)row * 2048 + col] = f2bf(o[d0][r] * inv[r]);
    }
}

// ---------------- launch ----------------
extern "C" void kernel_launch(void* const* d_in, const int* in_sizes, int n_in,
                              void* d_out, int out_size, void* d_ws, size_t ws_size,
                              hipStream_t stream) {
  const float* x  = (const float*)d_in[0];
  const int* mask = (const int*)d_in[1];
  const float* Wq = (const float*)d_in[2];
  const float* bq = (const float*)d_in[3];
  const float* Wk = (const float*)d_in[4];
  const float* bk = (const float*)d_in[5];
  const float* Wv = (const float*)d_in[6];
  const float* bv = (const float*)d_in[7];
  const float* Wo = (const float*)d_in[8];
  const float* bo = (const float*)d_in[9];
  const float* asc = (const float*)d_in[10];

  // ws layout (needs ~97 MB):
  //   [0,16M)   x_bf16, reused as ctx after QKV GEMM
  //   [16M,40M) W_qkv bf16; first 16M reused as V^T after QKV GEMM
  //   [40M,48M) Wo bf16
  //   [48M,..)  bias_qkv f32 (24KB), flags (8KB) at 48M+64K
  //   [49M,97M) QKV bf16 [4096][6144]
  char* ws = (char*)d_ws;
  unsigned short* xb   = (unsigned short*)(ws);
  unsigned short* wqkv = (unsigned short*)(ws + ((size_t)16 << 20));
  unsigned short* wob  = (unsigned short*)(ws + ((size_t)40 << 20));
  float* biasq         = (float*)(ws + ((size_t)48 << 20));
  int* flags           = (int*)(ws + ((size_t)48 << 20) + (64 << 10));
  unsigned short* qkv  = (unsigned short*)(ws + ((size_t)49 << 20));
  unsigned short* VT   = wqkv;   // reuse
  unsigned short* ctx  = xb;     // reuse
  float* out = (float*)d_out;

  hipLaunchKernelGGL(cast_kernel, dim3(2048), dim3(256), 0, stream,
                     x, Wq, Wk, Wv, Wo, bq, bk, bv, xb, wqkv, wob, biasq);
  hipLaunchKernelGGL(maskflag_kernel, dim3(2048), dim3(256), 0, stream, mask, flags);
  hipLaunchKernelGGL((gemm_bt<true>), dim3(48, 32), dim3(256), 0, stream,
                     xb, wqkv, (void*)qkv, biasq, 6144, 2048);
  hipLaunchKernelGGL(norm_vt_kernel, dim3(1024), dim3(256), 0, stream, qkv, VT, asc);
  hipLaunchKernelGGL(flash_kernel, dim3(1024), dim3(256), 0, stream,
                     qkv, VT, flags, mask, ctx);
  hipLaunchKernelGGL((gemm_bt<false>), dim3(16, 32), dim3(256), 0, stream,
                     ctx, wob, (void*)out, bo, 2048, 2048);
}

// Round 6
// 490.523 us; speedup vs baseline: 1.1261x; 1.1261x over previous
//
#include <hip/hip_runtime.h>
#include <hip/hip_bf16.h>
#include <stdint.h>

typedef __attribute__((ext_vector_type(8))) short short8;
typedef __attribute__((ext_vector_type(4))) float f32x4;
typedef __attribute__((ext_vector_type(4))) unsigned short ushort4v;
typedef __attribute__((ext_vector_type(4))) float float4v;
typedef __attribute__((ext_vector_type(4))) int int4v;

#define GLL16(gp, lp)                                                        \
  __builtin_amdgcn_global_load_lds(                                          \
      (const __attribute__((address_space(1))) void*)(gp),                   \
      (__attribute__((address_space(3))) void*)(lp), 16, 0, 0)

__device__ __forceinline__ unsigned short f2bf(float f) {
  union { float f; unsigned u; } v; v.f = f;
  unsigned r = v.u + 0x7FFFu + ((v.u >> 16) & 1u);
  return (unsigned short)(r >> 16);
}
__device__ __forceinline__ float bf2f(unsigned short h) {
  union { unsigned u; float f; } v; v.u = ((unsigned)h) << 16;
  return v.f;
}
__device__ __forceinline__ unsigned pkbf(float a, float b) {
  union { __hip_bfloat162 h; unsigned u; } v;
  v.h = __float22bfloat162_rn(make_float2(a, b));   // v_cvt_pk_bf16_f32
  return v.u;
}

// ---------------- cast fp32 -> bf16, concat weights & biases ----------------
__global__ __launch_bounds__(256) void cast_kernel(
    const float* __restrict__ x, const float* __restrict__ Wq,
    const float* __restrict__ Wk, const float* __restrict__ Wv,
    const float* __restrict__ Wo, const float* __restrict__ bq,
    const float* __restrict__ bk, const float* __restrict__ bv,
    unsigned short* __restrict__ xb, unsigned short* __restrict__ wqkv,
    unsigned short* __restrict__ wob, float* __restrict__ biasq) {
  const int X4 = 2097152, W4 = 1048576;            // float4 counts
  const int total = X4 + 4 * W4 + 1536;
  for (int i = blockIdx.x * 256 + threadIdx.x; i < total; i += gridDim.x * 256) {
    if (i < X4 + 4 * W4) {
      const float* src; unsigned short* dst;
      if (i < X4) { src = x + (size_t)i * 4; dst = xb + (size_t)i * 4; }
      else {
        int j = i - X4;
        if (j < 3 * W4) {
          const float* w = (j < W4) ? Wq : (j < 2 * W4 ? Wk : Wv);
          int j0 = (j < W4) ? j : (j < 2 * W4 ? j - W4 : j - 2 * W4);
          src = w + (size_t)j0 * 4; dst = wqkv + (size_t)j * 4;
        } else {
          int j0 = j - 3 * W4; src = Wo + (size_t)j0 * 4; dst = wob + (size_t)j0 * 4;
        }
      }
      float4v v = *(const float4v*)src;
      ushort4v o; o.x = f2bf(v.x); o.y = f2bf(v.y); o.z = f2bf(v.z); o.w = f2bf(v.w);
      *(ushort4v*)dst = o;
    } else {
      int j = i - (X4 + 4 * W4);                   // 0..1535 -> 6144 floats
      const float* src = (j < 512) ? bq + j * 4
                        : (j < 1024 ? bk + (j - 512) * 4 : bv + (j - 1024) * 4);
      *(float4v*)(biasq + j * 4) = *(const float4v*)src;
    }
  }
}

// ------------- per-128x64-tile mask summary (1 = all nonzero) -------------
__global__ __launch_bounds__(256) void maskflag_kernel(const int* __restrict__ mask,
                                                       int* __restrict__ flags) {
  const int bid = blockIdx.x;                      // b*512 + qt*32 + kt
  const int b = bid >> 9, qt = (bid >> 5) & 15, kt = bid & 31;
  const int t = threadIdx.x;
  const int* mb = mask + (size_t)b * 4194304;
  int ok = 1;
#pragma unroll
  for (int j = 0; j < 8; ++j) {
    int flat = t * 32 + j * 4;                     // 0..8188
    int r = flat >> 6, c = flat & 63;
    int4v v = *(const int4v*)(mb + (size_t)(qt * 128 + r) * 2048 + kt * 64 + c);
    ok &= (v.x != 0) & (v.y != 0) & (v.z != 0) & (v.w != 0);
  }
  int all = __syncthreads_and(ok);
  if (t == 0) flags[bid] = all;
}

// ---------------- m97-style bf16 GEMM: C[m,n] = A[m,:] . B[n,:] + bias[n] ----------------
template <bool OUT_BF16>
__global__ __launch_bounds__(256) void gemm_bt(
    const unsigned short* __restrict__ A, const unsigned short* __restrict__ B,
    void* __restrict__ C, const float* __restrict__ bias, int N, int K) {
  __shared__ unsigned short As[128 * 64];
  __shared__ unsigned short Bs[128 * 64];
  const int tid = threadIdx.x, lane = tid & 63;
  const int wid = __builtin_amdgcn_readfirstlane(tid >> 6);
  const int wr = wid >> 1, wc = wid & 1;
  const int bm = blockIdx.y, bn = blockIdx.x;
  const int g = lane >> 4, q15 = lane & 15;
  f32x4 acc[4][4];
#pragma unroll
  for (int i = 0; i < 4; ++i)
#pragma unroll
    for (int j = 0; j < 4; ++j) acc[i][j] = f32x4{0.f, 0.f, 0.f, 0.f};
  const size_t ldab = (size_t)K * 2;               // row stride bytes
  const int nkt = K >> 6;
  for (int kt = 0; kt < nkt; ++kt) {
#pragma unroll
    for (int i = 0; i < 4; ++i) {
      int c = i * 4 + wid;
      int o = c * 1024 + lane * 16;
      int row = o >> 7, colb = o & 127;            // 128B rows (64 bf16)
      GLL16((const char*)A + (size_t)(bm * 128 + row) * ldab + kt * 128 + colb,
            (char*)As + c * 1024);
      GLL16((const char*)B + (size_t)(bn * 128 + row) * ldab + kt * 128 + colb,
            (char*)Bs + c * 1024);
    }
    __syncthreads();
#pragma unroll
    for (int kk = 0; kk < 2; ++kk) {
      short8 af[4], bfv[4];
#pragma unroll
      for (int mf = 0; mf < 4; ++mf)
        af[mf] = *(const short8*)((const char*)As +
                 (wr * 64 + mf * 16 + q15) * 128 + kk * 64 + g * 16);
#pragma unroll
      for (int nf = 0; nf < 4; ++nf)
        bfv[nf] = *(const short8*)((const char*)Bs +
                  (wc * 64 + nf * 16 + q15) * 128 + kk * 64 + g * 16);
#pragma unroll
      for (int mf = 0; mf < 4; ++mf)
#pragma unroll
        for (int nf = 0; nf < 4; ++nf)
          acc[mf][nf] = __builtin_amdgcn_mfma_f32_16x16x32_bf16(
              af[mf], bfv[nf], acc[mf][nf], 0, 0, 0);
    }
    __syncthreads();
  }
#pragma unroll
  for (int nf = 0; nf < 4; ++nf) {
    int col = bn * 128 + wc * 64 + nf * 16 + q15;
    float bv = bias[col];
#pragma unroll
    for (int mf = 0; mf < 4; ++mf) {
#pragma unroll
      for (int r = 0; r < 4; ++r) {
        int row = bm * 128 + wr * 64 + mf * 16 + g * 4 + r;
        float v = acc[mf][nf][r] + bv;
        if (OUT_BF16)
          ((unsigned short*)C)[(size_t)row * N + col] = f2bf(v);
        else
          ((float*)C)[(size_t)row * N + col] = v;
      }
    }
  }
}

// ---------------- L2-norm q,k in place; V -> V^T[b,h,128,S] ----------------
// q additionally scaled by attention_scale * log2(e)  (flash works in exp2 domain)
__global__ __launch_bounds__(256) void norm_vt_kernel(
    unsigned short* __restrict__ QKV, unsigned short* __restrict__ VT,
    const float* __restrict__ scale_p) {
  __shared__ unsigned short vt[128 * 72];          // 72 pad: 144B rows, 16B aligned
  const int bid = blockIdx.x;                      // b*512 + h*32 + st
  const int b = bid >> 9, h = (bid >> 5) & 15, st = bid & 31;
  const int t = threadIdx.x;
  const int r = t >> 2, qd = t & 3;                // 64 rows x 4 quarters of 32
  const float scale = scale_p[0] * 1.4426950408889634f;
  unsigned short* rowp = QKV + (size_t)(b * 2048 + st * 64 + r) * 6144;
#pragma unroll
  for (int part = 0; part < 2; ++part) {           // 0=q (scaled), 1=k
    unsigned short* p = rowp + part * 2048 + h * 128 + qd * 32;
    short8 v[4];
    float ss = 0.f;
#pragma unroll
    for (int j = 0; j < 4; ++j) {
      v[j] = *(const short8*)(p + j * 8);
#pragma unroll
      for (int e = 0; e < 8; ++e) {
        float f = bf2f((unsigned short)v[j][e]);
        ss += f * f;
      }
    }
    ss += __shfl_xor(ss, 1, 64);
    ss += __shfl_xor(ss, 2, 64);
    float inv = 1.0f / fmaxf(sqrtf(ss), 1e-12f);
    if (part == 0) inv *= scale;
#pragma unroll
    for (int j = 0; j < 4; ++j) {
      short8 w;
#pragma unroll
      for (int e = 0; e < 8; ++e)
        w[e] = (short)f2bf(bf2f((unsigned short)v[j][e]) * inv);
      *(short8*)(p + j * 8) = w;
    }
  }
  {                                                // V tile transpose via LDS
    const unsigned short* p = rowp + 4096 + h * 128 + qd * 32;
#pragma unroll
    for (int j = 0; j < 4; ++j) {
      short8 v = *(const short8*)(p + j * 8);
#pragma unroll
      for (int e = 0; e < 8; ++e) {
        int d = qd * 32 + j * 8 + e;
        vt[d * 72 + r] = (unsigned short)v[e];
      }
    }
  }
  __syncthreads();
  {
    const int d = t >> 1, half = t & 1;
    unsigned short* dst = VT + ((size_t)(b * 16 + h) * 128 + d) * 2048 + st * 64 + half * 32;
#pragma unroll
    for (int j = 0; j < 4; ++j)
      *(short8*)(dst + j * 8) = *(const short8*)(&vt[d * 72 + half * 32 + j * 8]);
  }
}

// -------- flash attention: per (b,h,128 q-rows) block, 8 waves, dbuf K/V --------
// Swapped QK^T (S^T = K.Q) so softmax state lives in the q = lane&15 domain;
// PV computed as O^T = V^T . P^T; P exchanged lane-to-lane in registers.
__global__ __launch_bounds__(512, 4) void flash_kernel(
    const unsigned short* __restrict__ QKV, const unsigned short* __restrict__ VT,
    const int* __restrict__ flags, const int* __restrict__ mask,
    unsigned short* __restrict__ ctx) {
  __shared__ char lds[65536];                      // 2 x (Ks 16KB | Vs 16KB)
  const int tid = threadIdx.x, lane = tid & 63;
  const int wid = __builtin_amdgcn_readfirstlane(tid >> 6);
  const int g = lane >> 4, q15 = lane & 15;
  const int bid = blockIdx.x;                      // b*256 + h*16 + qt
  const int b = bid >> 8, h = (bid >> 4) & 15, qt = bid & 15;

  unsigned fb = 0;
#pragma unroll 1
  for (int i = 0; i < 32; ++i)
    fb |= (unsigned)(flags[b * 512 + qt * 32 + i] != 0) << i;

  // Q fragments (B operand): lane holds Q[q=q15][d = kk*32 + g*8 + e]
  short8 qf[4];
  {
    const char* qbase = (const char*)QKV +
        (size_t)(b * 2048 + qt * 128 + wid * 16 + q15) * 12288 + h * 256;
#pragma unroll
    for (int kk = 0; kk < 4; ++kk)
      qf[kk] = *(const short8*)(qbase + kk * 64 + g * 16);
  }

  // staging descriptors: waves 0-3 stage K (16 chunks), waves 4-7 stage V^T
  const char* sptr;
  size_t sbase[4]; int ldso[4]; size_t kstep;
  if (wid < 4) {
    sptr = (const char*)QKV; kstep = (size_t)64 * 12288;
#pragma unroll
    for (int i = 0; i < 4; ++i) {
      int c = wid * 4 + i;                         // K chunk, rows 4c..4c+3 (256B rows)
      int row = c * 4 + g;
      int scol = ((lane & 15) * 16) ^ ((row & 7) << 4);
      sbase[i] = (size_t)(b * 2048 + row) * 12288 + 4096 + h * 256 + scol;
      ldso[i] = c * 1024;
    }
  } else {
    sptr = (const char*)VT; kstep = 128;
#pragma unroll
    for (int i = 0; i < 4; ++i) {
      int c2 = (wid - 4) * 4 + i;                  // V chunk, rows 8c2..8c2+7 (128B rows)
      int d = c2 * 8 + (lane >> 3);
      int scol = ((lane & 7) * 16) ^ ((d & 7) << 4);
      sbase[i] = ((size_t)((b * 16 + h) * 128 + d)) * 4096 + scol;
      ldso[i] = 16384 + c2 * 1024;
    }
  }

  f32x4 o[8];
#pragma unroll
  for (int i = 0; i < 8; ++i) o[i] = f32x4{0.f, 0.f, 0.f, 0.f};
  float mrun = -1e30f, lrun = 0.f;
  const int l0 = q15 + 16 * ((2 * g) & 3), l1 = l0 + 16;
  const bool hi = ((g >> 1) & 1) != 0;

#pragma unroll
  for (int i = 0; i < 4; ++i) GLL16(sptr + sbase[i], lds + ldso[i]);
  __syncthreads();

  for (int kt = 0; kt < 32; ++kt) {
    const int cur = kt & 1;
    if (kt < 31) {
#pragma unroll
      for (int i = 0; i < 4; ++i)
        GLL16(sptr + sbase[i] + (size_t)(kt + 1) * kstep,
              lds + (cur ^ 1) * 32768 + ldso[i]);
    }
    const char* Ks = lds + cur * 32768;
    const char* Vs = Ks + 16384;

    // ---- S^T = K . Q : lane holds S^T[key = nf*16 + g*4 + r][q = q15] ----
    f32x4 s[4];
#pragma unroll
    for (int nf = 0; nf < 4; ++nf) s[nf] = f32x4{0.f, 0.f, 0.f, 0.f};
#pragma unroll
    for (int nf = 0; nf < 4; ++nf) {
      const char* kb = Ks + (nf * 16 + q15) * 256;
      const int sw = (q15 & 7) << 4;
#pragma unroll
      for (int kk = 0; kk < 4; ++kk) {
        short8 kf = *(const short8*)(kb + ((kk * 64 + g * 16) ^ sw));
        s[nf] = __builtin_amdgcn_mfma_f32_16x16x32_bf16(kf, qf[kk], s[nf], 0, 0, 0);
      }
    }

    if (!((fb >> kt) & 1)) {                       // rare slow path
#pragma unroll
      for (int nf = 0; nf < 4; ++nf)
#pragma unroll
        for (int r = 0; r < 4; ++r) {
          int key = kt * 64 + nf * 16 + g * 4 + r;
          int q = qt * 128 + wid * 16 + q15;
          if (mask[(size_t)b * 4194304 + (size_t)q * 2048 + key] == 0)
            s[nf][r] = -__builtin_inff();
        }
    }

    // ---- online softmax (exp2 domain; q pre-scaled by log2e) ----
    float pmax = s[0][0];
#pragma unroll
    for (int nf = 0; nf < 4; ++nf)
#pragma unroll
      for (int r = 0; r < 4; ++r) pmax = fmaxf(pmax, s[nf][r]);
    pmax = fmaxf(pmax, __shfl_xor(pmax, 16, 64));
    pmax = fmaxf(pmax, __shfl_xor(pmax, 32, 64));

    if (__any(pmax - mrun > 8.0f)) {               // defer-max: rarely taken
      float mnew = fmaxf(mrun, pmax);
      float sc = exp2f(mrun - mnew);
      mrun = mnew; lrun *= sc;
#pragma unroll
      for (int d0 = 0; d0 < 8; ++d0)
#pragma unroll
        for (int r = 0; r < 4; ++r) o[d0][r] *= sc;
    }

    float rs = 0.f;
#pragma unroll
    for (int nf = 0; nf < 4; ++nf)
#pragma unroll
      for (int r = 0; r < 4; ++r) {
        float p = exp2f(s[nf][r] - mrun);
        s[nf][r] = p; rs += p;
      }
    rs += __shfl_xor(rs, 16, 64);
    rs += __shfl_xor(rs, 32, 64);
    lrun += rs;

    // ---- P^T -> bf16 packed, exchanged in-register to B-frag layout ----
    unsigned pk[4][2];
#pragma unroll
    for (int nf = 0; nf < 4; ++nf) {
      pk[nf][0] = pkbf(s[nf][0], s[nf][1]);
      pk[nf][1] = pkbf(s[nf][2], s[nf][3]);
    }

#pragma unroll
    for (int kk2 = 0; kk2 < 2; ++kk2) {
      unsigned w0a = __shfl(pk[2*kk2][0], l0, 64), w0b = __shfl(pk[2*kk2+1][0], l0, 64);
      unsigned w1a = __shfl(pk[2*kk2][1], l0, 64), w1b = __shfl(pk[2*kk2+1][1], l0, 64);
      unsigned w2a = __shfl(pk[2*kk2][0], l1, 64), w2b = __shfl(pk[2*kk2+1][0], l1, 64);
      unsigned w3a = __shfl(pk[2*kk2][1], l1, 64), w3b = __shfl(pk[2*kk2+1][1], l1, 64);
      union { unsigned u[4]; short8 s8; } pu;
      pu.u[0] = hi ? w0b : w0a;
      pu.u[1] = hi ? w1b : w1a;
      pu.u[2] = hi ? w2b : w2a;
      pu.u[3] = hi ? w3b : w3a;
      // ---- O^T += V^T . P^T : lane holds O^T[d = d0*16+g*4+r][q = q15] ----
#pragma unroll
      for (int d0 = 0; d0 < 8; ++d0) {
        int d = d0 * 16 + q15;
        short8 vf = *(const short8*)(Vs + d * 128 +
                     ((kk2 * 64 + g * 16) ^ ((d & 7) << 4)));
        o[d0] = __builtin_amdgcn_mfma_f32_16x16x32_bf16(vf, pu.s8, o[d0], 0, 0, 0);
      }
    }
    __syncthreads();
  }

  // ---- epilogue: normalize, transpose via LDS, coalesced store ----
  float invl = 1.0f / lrun;
  {
    char* ost = lds;                               // reuse buffer 0 (32KB)
    int rb = (wid * 16 + q15) * 256;
    int sw = (q15 & 7) << 4;
#pragma unroll
    for (int d0 = 0; d0 < 8; ++d0)
#pragma unroll
      for (int j = 0; j < 2; ++j) {
        unsigned w = pkbf(o[d0][2 * j] * invl, o[d0][2 * j + 1] * invl);
        *(unsigned*)(ost + rb + ((d0 * 32 + g * 8 + j * 4) ^ sw)) = w;
      }
  }
  __syncthreads();
#pragma unroll
  for (int p = 0; p < 4; ++p) {
    int flat = p * 512 + tid;
    int row = flat >> 4, c16 = flat & 15;
    short8 v = *(const short8*)(lds + row * 256 + ((c16 * 16) ^ ((row & 7) << 4)));
    *(short8*)((char*)ctx + (size_t)(b * 2048 + qt * 128 + row) * 4096 +
               h * 256 + c16 * 16) = v;
  }
}

// ---------------- launch ----------------
extern "C" void kernel_launch(void* const* d_in, const int* in_sizes, int n_in,
                              void* d_out, int out_size, void* d_ws, size_t ws_size,
                              hipStream_t stream) {
  const float* x  = (const float*)d_in[0];
  const int* mask = (const int*)d_in[1];
  const float* Wq = (const float*)d_in[2];
  const float* bq = (const float*)d_in[3];
  const float* Wk = (const float*)d_in[4];
  const float* bk = (const float*)d_in[5];
  const float* Wv = (const float*)d_in[6];
  const float* bv = (const float*)d_in[7];
  const float* Wo = (const float*)d_in[8];
  const float* bo = (const float*)d_in[9];
  const float* asc = (const float*)d_in[10];

  char* ws = (char*)d_ws;
  unsigned short* xb   = (unsigned short*)(ws);
  unsigned short* wqkv = (unsigned short*)(ws + ((size_t)16 << 20));
  unsigned short* wob  = (unsigned short*)(ws + ((size_t)40 << 20));
  float* biasq         = (float*)(ws + ((size_t)48 << 20));
  int* flags           = (int*)(ws + ((size_t)48 << 20) + (64 << 10));
  unsigned short* qkv  = (unsigned short*)(ws + ((size_t)49 << 20));
  unsigned short* VT   = wqkv;   // reuse
  unsigned short* ctx  = xb;     // reuse
  float* out = (float*)d_out;

  hipLaunchKernelGGL(cast_kernel, dim3(2048), dim3(256), 0, stream,
                     x, Wq, Wk, Wv, Wo, bq, bk, bv, xb, wqkv, wob, biasq);
  hipLaunchKernelGGL(maskflag_kernel, dim3(1024), dim3(256), 0, stream, mask, flags);
  hipLaunchKernelGGL((gemm_bt<true>), dim3(48, 32), dim3(256), 0, stream,
                     xb, wqkv, (void*)qkv, biasq, 6144, 2048);
  hipLaunchKernelGGL(norm_vt_kernel, dim3(1024), dim3(256), 0, stream, qkv, VT, asc);
  hipLaunchKernelGGL(flash_kernel, dim3(512), dim3(512), 0, stream,
                     qkv, VT, flags, mask, ctx);
  hipLaunchKernelGGL((gemm_bt<false>), dim3(16, 32), dim3(256), 0, stream,
                     ctx, wob, (void*)out, bo, 2048, 2048);
}

// Round 13
// 476.005 us; speedup vs baseline: 1.1605x; 1.0305x over previous
//
#include <hip/hip_runtime.h>
#include <hip/hip_bf16.h>
#include <stdint.h>

typedef __attribute__((ext_vector_type(8))) short short8;
typedef __attribute__((ext_vector_type(4))) float f32x4;
typedef __attribute__((ext_vector_type(4))) unsigned short ushort4v;
typedef __attribute__((ext_vector_type(4))) float float4v;
typedef __attribute__((ext_vector_type(4))) int int4v;

#define GLL16(gp, lp)                                                        \
  __builtin_amdgcn_global_load_lds(                                          \
      (const __attribute__((address_space(1))) void*)(gp),                   \
      (__attribute__((address_space(3))) void*)(lp), 16, 0, 0)

__device__ __forceinline__ unsigned short f2bf(float f) {
  union { float f; unsigned u; } v; v.f = f;
  unsigned r = v.u + 0x7FFFu + ((v.u >> 16) & 1u);
  return (unsigned short)(r >> 16);
}
__device__ __forceinline__ float bf2f(unsigned short h) {
  union { unsigned u; float f; } v; v.u = ((unsigned)h) << 16;
  return v.f;
}
__device__ __forceinline__ unsigned pkbf(float a, float b) {
  union { __hip_bfloat162 h; unsigned u; } v;
  v.h = __float22bfloat162_rn(make_float2(a, b));   // v_cvt_pk_bf16_f32
  return v.u;
}

// ---------------- cast fp32 -> bf16, concat weights & biases ----------------
__global__ __launch_bounds__(256) void cast_kernel(
    const float* __restrict__ x, const float* __restrict__ Wq,
    const float* __restrict__ Wk, const float* __restrict__ Wv,
    const float* __restrict__ Wo, const float* __restrict__ bq,
    const float* __restrict__ bk, const float* __restrict__ bv,
    unsigned short* __restrict__ xb, unsigned short* __restrict__ wqkv,
    unsigned short* __restrict__ wob, float* __restrict__ biasq) {
  const int X4 = 2097152, W4 = 1048576;            // float4 counts
  const int total = X4 + 4 * W4 + 1536;
  for (int i = blockIdx.x * 256 + threadIdx.x; i < total; i += gridDim.x * 256) {
    if (i < X4 + 4 * W4) {
      const float* src; unsigned short* dst;
      if (i < X4) { src = x + (size_t)i * 4; dst = xb + (size_t)i * 4; }
      else {
        int j = i - X4;
        if (j < 3 * W4) {
          const float* w = (j < W4) ? Wq : (j < 2 * W4 ? Wk : Wv);
          int j0 = (j < W4) ? j : (j < 2 * W4 ? j - W4 : j - 2 * W4);
          src = w + (size_t)j0 * 4; dst = wqkv + (size_t)j * 4;
        } else {
          int j0 = j - 3 * W4; src = Wo + (size_t)j0 * 4; dst = wob + (size_t)j0 * 4;
        }
      }
      float4v v = *(const float4v*)src;
      ushort4v o; o.x = f2bf(v.x); o.y = f2bf(v.y); o.z = f2bf(v.z); o.w = f2bf(v.w);
      *(ushort4v*)dst = o;
    } else {
      int j = i - (X4 + 4 * W4);                   // 0..1535 -> 6144 floats
      const float* src = (j < 512) ? bq + j * 4
                        : (j < 1024 ? bk + (j - 512) * 4 : bv + (j - 1024) * 4);
      *(float4v*)(biasq + j * 4) = *(const float4v*)src;
    }
  }
}

// ------------- per-128x64-tile mask summary (1 = all nonzero) -------------
__global__ __launch_bounds__(256) void maskflag_kernel(const int* __restrict__ mask,
                                                       int* __restrict__ flags) {
  const int bid = blockIdx.x;                      // b*512 + qt*32 + kt
  const int b = bid >> 9, qt = (bid >> 5) & 15, kt = bid & 31;
  const int t = threadIdx.x;
  const int* mb = mask + (size_t)b * 4194304;
  int ok = 1;
#pragma unroll
  for (int j = 0; j < 8; ++j) {
    int flat = t * 32 + j * 4;                     // 0..8188
    int r = flat >> 6, c = flat & 63;
    int4v v = *(const int4v*)(mb + (size_t)(qt * 128 + r) * 2048 + kt * 64 + c);
    ok &= (v.x != 0) & (v.y != 0) & (v.z != 0) & (v.w != 0);
  }
  int all = __syncthreads_and(ok);
  if (t == 0) flags[bid] = all;
}

// ---- 4-deep pipelined bf16 GEMM: C[m,n] = A[m,:].B[n,:] + bias[n] ----
// BM=128, BN=256, BK=32, K=2048 fixed. 8 waves (2Mx4N), 96KB LDS (4 bufs).
// Counted vmcnt(6) keeps 2 K-tiles of staging in flight across raw barriers.
// LDS layout: row-pair packed [R=r>>1][128B], inrow = ((r&1)<<6 | c) ^ ((R&7)<<4).
template <bool OUT_BF16>
__global__ __launch_bounds__(512, 2) void gemm_p4(
    const unsigned short* __restrict__ A, const unsigned short* __restrict__ B,
    void* __restrict__ C, const float* __restrict__ bias, int N) {
  __shared__ __attribute__((aligned(16))) char lds[98304]; // A:4x8KB@0, B:4x16KB@32768
  const int tid = threadIdx.x, lane = tid & 63;
  const int wid = __builtin_amdgcn_readfirstlane(tid >> 6);
  const int wr = wid >> 2, wc = wid & 3;
  const int g = lane >> 4, q15 = lane & 15;
  const int bm = blockIdx.y, bn = blockIdx.x;
  const size_t ldb = 4096;                         // K*2 bytes

  // staging sources (pre-swizzled so linear GLL dest + swizzled read match)
  const int Rt = tid >> 3;
  const int wp = ((tid & 7) * 16) ^ ((Rt & 7) << 4);
  const int sr = Rt * 2 + (wp >> 6), scb = wp & 63;
  const char* srcA  = (const char*)A + (size_t)(bm * 128 + sr) * ldb + scb;
  const char* srcB0 = (const char*)B + (size_t)(bn * 256 + sr) * ldb + scb;
  const char* srcB1 = (const char*)B + (size_t)(bn * 256 + 128 + sr) * ldb + scb;
  const int dA = tid * 16;

  // LDS read offsets (within a buffer)
  int aoff[4], boff[4];
#pragma unroll
  for (int m = 0; m < 4; ++m) {
    int r = wr * 64 + m * 16 + q15;
    aoff[m] = (r >> 1) * 128 + ((((r & 1) << 6) | (g << 4)) ^ (((r >> 1) & 7) << 4));
    int r2 = wc * 64 + m * 16 + q15;
    boff[m] = (r2 >> 1) * 128 + ((((r2 & 1) << 6) | (g << 4)) ^ (((r2 >> 1) & 7) << 4));
  }

  f32x4 acc[4][4];
#pragma unroll
  for (int i = 0; i < 4; ++i)
#pragma unroll
    for (int j = 0; j < 4; ++j) acc[i][j] = f32x4{0.f, 0.f, 0.f, 0.f};

#define STAGE(t) do { int d_ = (t) & 3; size_t ko_ = (size_t)(t) * 64;        \
    GLL16(srcA + ko_, lds + d_ * 8192 + dA);                                  \
    GLL16(srcB0 + ko_, lds + 32768 + d_ * 16384 + dA);                        \
    GLL16(srcB1 + ko_, lds + 32768 + d_ * 16384 + 8192 + dA); } while (0)

#define DSR(dst, off) asm volatile("ds_read_b128 %0, %1" : "=v"(dst)          \
    : "v"((__attribute__((address_space(3))) char*)(lds + (off))))

#define BARX do { __builtin_amdgcn_sched_barrier(0);                          \
    __builtin_amdgcn_s_barrier(); __builtin_amdgcn_sched_barrier(0); } while (0)

  auto compute = [&](int t) {
    const int ab = (t & 3) * 8192, bb = 32768 + (t & 3) * 16384;
    int4v a0, a1, a2, a3, b0, b1, b2, b3;
    DSR(a0, ab + aoff[0]); DSR(a1, ab + aoff[1]);
    DSR(a2, ab + aoff[2]); DSR(a3, ab + aoff[3]);
    DSR(b0, bb + boff[0]); DSR(b1, bb + boff[1]);
    DSR(b2, bb + boff[2]); DSR(b3, bb + boff[3]);
    asm volatile("s_waitcnt lgkmcnt(0)" ::: "memory");
    __builtin_amdgcn_sched_barrier(0);
    short8 af[4] = {__builtin_bit_cast(short8, a0), __builtin_bit_cast(short8, a1),
                    __builtin_bit_cast(short8, a2), __builtin_bit_cast(short8, a3)};
    short8 bf[4] = {__builtin_bit_cast(short8, b0), __builtin_bit_cast(short8, b1),
                    __builtin_bit_cast(short8, b2), __builtin_bit_cast(short8, b3)};
    __builtin_amdgcn_s_setprio(1);
#pragma unroll
    for (int m = 0; m < 4; ++m)
#pragma unroll
      for (int n = 0; n < 4; ++n)
        acc[m][n] = __builtin_amdgcn_mfma_f32_16x16x32_bf16(af[m], bf[n], acc[m][n], 0, 0, 0);
    __builtin_amdgcn_s_setprio(0);
  };

  STAGE(0); STAGE(1); STAGE(2);
  for (int t = 0; t < 61; ++t) {
    STAGE(t + 3);
    asm volatile("s_waitcnt vmcnt(6)" ::: "memory");
    BARX;
    compute(t);
    BARX;
  }
  asm volatile("s_waitcnt vmcnt(3)" ::: "memory");
  BARX; compute(61); BARX;
  asm volatile("s_waitcnt vmcnt(0)" ::: "memory");
  BARX; compute(62); BARX;
  compute(63);

  // epilogue
#pragma unroll
  for (int nf = 0; nf < 4; ++nf) {
    int col = bn * 256 + wc * 64 + nf * 16 + q15;
    float bv = bias[col];
#pragma unroll
    for (int mf = 0; mf < 4; ++mf) {
#pragma unroll
      for (int r = 0; r < 4; ++r) {
        int row = bm * 128 + wr * 64 + mf * 16 + g * 4 + r;
        float v = acc[mf][nf][r] + bv;
        if (OUT_BF16)
          ((unsigned short*)C)[(size_t)row * N + col] = f2bf(v);
        else
          ((float*)C)[(size_t)row * N + col] = v;
      }
    }
  }
#undef STAGE
#undef DSR
#undef BARX
}

// ---------------- L2-norm q,k in place; V -> V^T[b,h,128,S] ----------------
// q additionally scaled by attention_scale * log2(e)  (flash works in exp2 domain)
__global__ __launch_bounds__(256) void norm_vt_kernel(
    unsigned short* __restrict__ QKV, unsigned short* __restrict__ VT,
    const float* __restrict__ scale_p) {
  __shared__ unsigned short vt[128 * 72];          // 72 pad: 144B rows, 16B aligned
  const int bid = blockIdx.x;                      // b*512 + h*32 + st
  const int b = bid >> 9, h = (bid >> 5) & 15, st = bid & 31;
  const int t = threadIdx.x;
  const int r = t >> 2, qd = t & 3;                // 64 rows x 4 quarters of 32
  const float scale = scale_p[0] * 1.4426950408889634f;
  unsigned short* rowp = QKV + (size_t)(b * 2048 + st * 64 + r) * 6144;
#pragma unroll
  for (int part = 0; part < 2; ++part) {           // 0=q (scaled), 1=k
    unsigned short* p = rowp + part * 2048 + h * 128 + qd * 32;
    short8 v[4];
    float ss = 0.f;
#pragma unroll
    for (int j = 0; j < 4; ++j) {
      v[j] = *(const short8*)(p + j * 8);
#pragma unroll
      for (int e = 0; e < 8; ++e) {
        float f = bf2f((unsigned short)v[j][e]);
        ss += f * f;
      }
    }
    ss += __shfl_xor(ss, 1, 64);
    ss += __shfl_xor(ss, 2, 64);
    float inv = 1.0f / fmaxf(sqrtf(ss), 1e-12f);
    if (part == 0) inv *= scale;
#pragma unroll
    for (int j = 0; j < 4; ++j) {
      short8 w;
#pragma unroll
      for (int e = 0; e < 8; ++e)
        w[e] = (short)f2bf(bf2f((unsigned short)v[j][e]) * inv);
      *(short8*)(p + j * 8) = w;
    }
  }
  {                                                // V tile transpose via LDS
    const unsigned short* p = rowp + 4096 + h * 128 + qd * 32;
#pragma unroll
    for (int j = 0; j < 4; ++j) {
      short8 v = *(const short8*)(p + j * 8);
#pragma unroll
      for (int e = 0; e < 8; ++e) {
        int d = qd * 32 + j * 8 + e;
        vt[d * 72 + r] = (unsigned short)v[e];
      }
    }
  }
  __syncthreads();
  {
    const int d = t >> 1, half = t & 1;
    unsigned short* dst = VT + ((size_t)(b * 16 + h) * 128 + d) * 2048 + st * 64 + half * 32;
#pragma unroll
    for (int j = 0; j < 4; ++j)
      *(short8*)(dst + j * 8) = *(const short8*)(&vt[d * 72 + half * 32 + j * 8]);
  }
}

// -------- flash attention: per (b,h,128 q-rows) block, 8 waves, dbuf K/V --------
// Swapped QK^T (S^T = K.Q) so softmax state lives in the q = lane&15 domain;
// PV computed as O^T = V^T . P^T; P exchanged lane-to-lane in registers.
__global__ __launch_bounds__(512, 4) void flash_kernel(
    const unsigned short* __restrict__ QKV, const unsigned short* __restrict__ VT,
    const int* __restrict__ flags, const int* __restrict__ mask,
    unsigned short* __restrict__ ctx) {
  __shared__ char lds[65536];                      // 2 x (Ks 16KB | Vs 16KB)
  const int tid = threadIdx.x, lane = tid & 63;
  const int wid = __builtin_amdgcn_readfirstlane(tid >> 6);
  const int g = lane >> 4, q15 = lane & 15;
  const int bid = blockIdx.x;                      // b*256 + h*16 + qt
  const int b = bid >> 8, h = (bid >> 4) & 15, qt = bid & 15;

  unsigned fb = 0;
#pragma unroll 1
  for (int i = 0; i < 32; ++i)
    fb |= (unsigned)(flags[b * 512 + qt * 32 + i] != 0) << i;

  // Q fragments (B operand): lane holds Q[q=q15][d = kk*32 + g*8 + e]
  short8 qf[4];
  {
    const char* qbase = (const char*)QKV +
        (size_t)(b * 2048 + qt * 128 + wid * 16 + q15) * 12288 + h * 256;
#pragma unroll
    for (int kk = 0; kk < 4; ++kk)
      qf[kk] = *(const short8*)(qbase + kk * 64 + g * 16);
  }

  // staging descriptors: waves 0-3 stage K (16 chunks), waves 4-7 stage V^T
  const char* sptr;
  size_t sbase[4]; int ldso[4]; size_t kstep;
  if (wid < 4) {
    sptr = (const char*)QKV; kstep = (size_t)64 * 12288;
#pragma unroll
    for (int i = 0; i < 4; ++i) {
      int c = wid * 4 + i;                         // K chunk, rows 4c..4c+3 (256B rows)
      int row = c * 4 + g;
      int scol = ((lane & 15) * 16) ^ ((row & 7) << 4);
      sbase[i] = (size_t)(b * 2048 + row) * 12288 + 4096 + h * 256 + scol;
      ldso[i] = c * 1024;
    }
  } else {
    sptr = (const char*)VT; kstep = 128;
#pragma unroll
    for (int i = 0; i < 4; ++i) {
      int c2 = (wid - 4) * 4 + i;                  // V chunk, rows 8c2..8c2+7 (128B rows)
      int d = c2 * 8 + (lane >> 3);
      int scol = ((lane & 7) * 16) ^ ((d & 7) << 4);
      sbase[i] = ((size_t)((b * 16 + h) * 128 + d)) * 4096 + scol;
      ldso[i] = 16384 + c2 * 1024;
    }
  }

  f32x4 o[8];
#pragma unroll
  for (int i = 0; i < 8; ++i) o[i] = f32x4{0.f, 0.f, 0.f, 0.f};
  float mrun = -1e30f, lrun = 0.f;
  const int l0 = q15 + 16 * ((2 * g) & 3), l1 = l0 + 16;
  const bool hi = ((g >> 1) & 1) != 0;

#pragma unroll
  for (int i = 0; i < 4; ++i) GLL16(sptr + sbase[i], lds + ldso[i]);
  __syncthreads();

  for (int kt = 0; kt < 32; ++kt) {
    const int cur = kt & 1;
    if (kt < 31) {
#pragma unroll
      for (int i = 0; i < 4; ++i)
        GLL16(sptr + sbase[i] + (size_t)(kt + 1) * kstep,
              lds + (cur ^ 1) * 32768 + ldso[i]);
    }
    const char* Ks = lds + cur * 32768;
    const char* Vs = Ks + 16384;

    // ---- S^T = K . Q : lane holds S^T[key = nf*16 + g*4 + r][q = q15] ----
    f32x4 s[4];
#pragma unroll
    for (int nf = 0; nf < 4; ++nf) s[nf] = f32x4{0.f, 0.f, 0.f, 0.f};
#pragma unroll
    for (int nf = 0; nf < 4; ++nf) {
      const char* kb = Ks + (nf * 16 + q15) * 256;
      const int sw = (q15 & 7) << 4;
#pragma unroll
      for (int kk = 0; kk < 4; ++kk) {
        short8 kf = *(const short8*)(kb + ((kk * 64 + g * 16) ^ sw));
        s[nf] = __builtin_amdgcn_mfma_f32_16x16x32_bf16(kf, qf[kk], s[nf], 0, 0, 0);
      }
    }

    if (!((fb >> kt) & 1)) {                       // rare slow path
#pragma unroll
      for (int nf = 0; nf < 4; ++nf)
#pragma unroll
        for (int r = 0; r < 4; ++r) {
          int key = kt * 64 + nf * 16 + g * 4 + r;
          int q = qt * 128 + wid * 16 + q15;
          if (mask[(size_t)b * 4194304 + (size_t)q * 2048 + key] == 0)
            s[nf][r] = -__builtin_inff();
        }
    }

    // ---- online softmax (exp2 domain; q pre-scaled by log2e) ----
    float pmax = s[0][0];
#pragma unroll
    for (int nf = 0; nf < 4; ++nf)
#pragma unroll
      for (int r = 0; r < 4; ++r) pmax = fmaxf(pmax, s[nf][r]);
    pmax = fmaxf(pmax, __shfl_xor(pmax, 16, 64));
    pmax = fmaxf(pmax, __shfl_xor(pmax, 32, 64));

    if (__any(pmax - mrun > 8.0f)) {               // defer-max: rarely taken
      float mnew = fmaxf(mrun, pmax);
      float sc = exp2f(mrun - mnew);
      mrun = mnew; lrun *= sc;
#pragma unroll
      for (int d0 = 0; d0 < 8; ++d0)
#pragma unroll
        for (int r = 0; r < 4; ++r) o[d0][r] *= sc;
    }

    float rs = 0.f;
#pragma unroll
    for (int nf = 0; nf < 4; ++nf)
#pragma unroll
      for (int r = 0; r < 4; ++r) {
        float p = exp2f(s[nf][r] - mrun);
        s[nf][r] = p; rs += p;
      }
    rs += __shfl_xor(rs, 16, 64);
    rs += __shfl_xor(rs, 32, 64);
    lrun += rs;

    // ---- P^T -> bf16 packed, exchanged in-register to B-frag layout ----
    unsigned pk[4][2];
#pragma unroll
    for (int nf = 0; nf < 4; ++nf) {
      pk[nf][0] = pkbf(s[nf][0], s[nf][1]);
      pk[nf][1] = pkbf(s[nf][2], s[nf][3]);
    }

#pragma unroll
    for (int kk2 = 0; kk2 < 2; ++kk2) {
      unsigned w0a = __shfl(pk[2*kk2][0], l0, 64), w0b = __shfl(pk[2*kk2+1][0], l0, 64);
      unsigned w1a = __shfl(pk[2*kk2][1], l0, 64), w1b = __shfl(pk[2*kk2+1][1], l0, 64);
      unsigned w2a = __shfl(pk[2*kk2][0], l1, 64), w2b = __shfl(pk[2*kk2+1][0], l1, 64);
      unsigned w3a = __shfl(pk[2*kk2][1], l1, 64), w3b = __shfl(pk[2*kk2+1][1], l1, 64);
      union { unsigned u[4]; short8 s8; } pu;
      pu.u[0] = hi ? w0b : w0a;
      pu.u[1] = hi ? w1b : w1a;
      pu.u[2] = hi ? w2b : w2a;
      pu.u[3] = hi ? w3b : w3a;
      // ---- O^T += V^T . P^T : lane holds O^T[d = d0*16+g*4+r][q = q15] ----
#pragma unroll
      for (int d0 = 0; d0 < 8; ++d0) {
        int d = d0 * 16 + q15;
        short8 vf = *(const short8*)(Vs + d * 128 +
                     ((kk2 * 64 + g * 16) ^ ((d & 7) << 4)));
        o[d0] = __builtin_amdgcn_mfma_f32_16x16x32_bf16(vf, pu.s8, o[d0], 0, 0, 0);
      }
    }
    __syncthreads();
  }

  // ---- epilogue: normalize, transpose via LDS, coalesced store ----
  float invl = 1.0f / lrun;
  {
    char* ost = lds;                               // reuse buffer 0 (32KB)
    int rb = (wid * 16 + q15) * 256;
    int sw = (q15 & 7) << 4;
#pragma unroll
    for (int d0 = 0; d0 < 8; ++d0)
#pragma unroll
      for (int j = 0; j < 2; ++j) {
        unsigned w = pkbf(o[d0][2 * j] * invl, o[d0][2 * j + 1] * invl);
        *(unsigned*)(ost + rb + ((d0 * 32 + g * 8 + j * 4) ^ sw)) = w;
      }
  }
  __syncthreads();
#pragma unroll
  for (int p = 0; p < 4; ++p) {
    int flat = p * 512 + tid;
    int row = flat >> 4, c16 = flat & 15;
    short8 v = *(const short8*)(lds + row * 256 + ((c16 * 16) ^ ((row & 7) << 4)));
    *(short8*)((char*)ctx + (size_t)(b * 2048 + qt * 128 + row) * 4096 +
               h * 256 + c16 * 16) = v;
  }
}

// ---------------- launch ----------------
extern "C" void kernel_launch(void* const* d_in, const int* in_sizes, int n_in,
                              void* d_out, int out_size, void* d_ws, size_t ws_size,
                              hipStream_t stream) {
  const float* x  = (const float*)d_in[0];
  const int* mask = (const int*)d_in[1];
  const float* Wq = (const float*)d_in[2];
  const float* bq = (const float*)d_in[3];
  const float* Wk = (const float*)d_in[4];
  const float* bk = (const float*)d_in[5];
  const float* Wv = (const float*)d_in[6];
  const float* bv = (const float*)d_in[7];
  const float* Wo = (const float*)d_in[8];
  const float* bo = (const float*)d_in[9];
  const float* asc = (const float*)d_in[10];

  char* ws = (char*)d_ws;
  unsigned short* xb   = (unsigned short*)(ws);
  unsigned short* wqkv = (unsigned short*)(ws + ((size_t)16 << 20));
  unsigned short* wob  = (unsigned short*)(ws + ((size_t)40 << 20));
  float* biasq         = (float*)(ws + ((size_t)48 << 20));
  int* flags           = (int*)(ws + ((size_t)48 << 20) + (64 << 10));
  unsigned short* qkv  = (unsigned short*)(ws + ((size_t)49 << 20));
  unsigned short* VT   = wqkv;   // reuse
  unsigned short* ctx  = xb;     // reuse
  float* out = (float*)d_out;

  hipLaunchKernelGGL(cast_kernel, dim3(2048), dim3(256), 0, stream,
                     x, Wq, Wk, Wv, Wo, bq, bk, bv, xb, wqkv, wob, biasq);
  hipLaunchKernelGGL(maskflag_kernel, dim3(1024), dim3(256), 0, stream, mask, flags);
  hipLaunchKernelGGL((gemm_p4<true>), dim3(24, 32), dim3(512), 0, stream,
                     xb, wqkv, (void*)qkv, biasq, 6144);
  hipLaunchKernelGGL(norm_vt_kernel, dim3(1024), dim3(256), 0, stream, qkv, VT, asc);
  hipLaunchKernelGGL(flash_kernel, dim3(512), dim3(512), 0, stream,
                     qkv, VT, flags, mask, ctx);
  hipLaunchKernelGGL((gemm_p4<false>), dim3(8, 32), dim3(512), 0, stream,
                     ctx, wob, (void*)out, bo, 2048);
}